// Round 1
// baseline (135.882 us; speedup 1.0000x reference)
//
#include <hip/hip_runtime.h>
#include <hip/hip_bf16.h>

#define NV 40962
#define NK 9
#define CIN 32
#define COUT 32
#define NBS 4
#define VT 256                 // transpose v-tile
#define TP 260                 // transpose LDS row stride (dwords)
#define NT 2561                // v-tiles of 16 in main kernel
#define NV81 (NV * 81)
#define NV9  (NV * 9)

typedef __attribute__((ext_vector_type(8))) short bf16x8;
typedef __attribute__((ext_vector_type(4))) float f32x4;
typedef __attribute__((ext_vector_type(2))) float f32x2;

// ---- packed f32 FMA/MUL, src0 broadcast from pair half (VOP3P op_sel)
#define PKFMA_L(A, G, R) asm("v_pk_fma_f32 %0, %1, %2, %0 op_sel:[0,0,0] op_sel_hi:[0,1,1]" : "+v"(A) : "v"(G), "v"(R))
#define PKFMA_H(A, G, R) asm("v_pk_fma_f32 %0, %1, %2, %0 op_sel:[1,0,0] op_sel_hi:[1,1,1]" : "+v"(A) : "v"(G), "v"(R))
#define PKMUL_L(A, G, R) asm("v_pk_mul_f32 %0, %1, %2 op_sel:[0,0] op_sel_hi:[0,1]" : "=v"(A) : "v"(G), "v"(R))
#define PKMUL_H(A, G, R) asm("v_pk_mul_f32 %0, %1, %2 op_sel:[1,0] op_sel_hi:[1,1]" : "=v"(A) : "v"(G), "v"(R))

#define ACC(cc, j) ((j) == 8 ? acc8[cc] : (((j) & 1) ? acc2[cc][(j) >> 1].y \
                                                     : acc2[cc][(j) >> 1].x))

// f32 pair -> packed bf16 dword (a=low), via v_cvt_pk_bf16_f32 (RNE)
__device__ __forceinline__ unsigned pkbf(float a, float b) {
    union { __hip_bfloat162 h2; unsigned u; } cv;
    cv.h2 = __float22bfloat162_rn(make_float2(a, b));
    return cv.u;
}

// ---------------------------------------------------------------------------
// Kernel 1: x [128 rows=(b*32+c)][V] f32 -> xt [v][coct(4)][b(4)][8ch] bf16
// (coct-major row layout so the main kernel's gather is one dense dwordx4
//  per lane with MFMA-compatible lane order: coct = lane>>4 = k-octet)
// ---------------------------------------------------------------------------
__global__ void __launch_bounds__(256) transpose_x_bf16(
    const float* __restrict__ x, unsigned* __restrict__ xtw)
{
    __shared__ unsigned T[16 * TP];
    const int b  = blockIdx.x & 3;
    const int v0 = (blockIdx.x >> 2) * VT;
    const int t  = threadIdx.x;
    const int w  = t >> 6;
    const int L  = t & 63;
    const bool full = (v0 + VT <= NV);

    #pragma unroll
    for (int i = 0; i < 4; ++i) {
        const int q = w + 4 * i;
        const float* rowA = x + (size_t)(b * 32 + 2 * q) * NV;
        const float* rowB = rowA + NV;
        #pragma unroll
        for (int h = 0; h < 2; ++h) {
            const int vl = 128 * h + 2 * L;
            float2 a, c;
            if (full) {
                a = *(const float2*)(rowA + v0 + vl);
                c = *(const float2*)(rowB + v0 + vl);
            } else {
                const int v = v0 + vl;
                a.x = (v     < NV) ? rowA[v]     : 0.0f;
                a.y = (v + 1 < NV) ? rowA[v + 1] : 0.0f;
                c.x = (v     < NV) ? rowB[v]     : 0.0f;
                c.y = (v + 1 < NV) ? rowB[v + 1] : 0.0f;
            }
            uint2 d;
            d.x = pkbf(a.x, c.x);
            d.y = pkbf(a.y, c.y);
            *(uint2*)&T[q * TP + vl] = d;
        }
    }
    __syncthreads();

    #pragma unroll
    for (int i = 0; i < 4; ++i) {
        const int vl = i * 64 + w * 16 + (L >> 2);
        const int u4 = L & 3;
        const int v  = v0 + vl;
        if (v < NV) {
            uint4 d;
            d.x = T[(4 * u4 + 0) * TP + vl];
            d.y = T[(4 * u4 + 1) * TP + vl];
            d.z = T[(4 * u4 + 2) * TP + vl];
            d.w = T[(4 * u4 + 3) * TP + vl];
            // row layout: [v][coct=u4][b][4 dwords] (byte = v*256 + u4*64 + b*16)
            *(uint4*)&xtw[(size_t)v * 64 + u4 * 16 + b * 4] = d;
        }
    }
}

// ---------------------------------------------------------------------------
// Kernel 2: conv weight f32 [o][c][j] -> bf16 wbf[o][k' = j*32 + c]
// (K-permuted GEMM order so B-frags can be built per-lane without LDS)
// ---------------------------------------------------------------------------
__global__ void __launch_bounds__(256) convert_w_bf16(
    const float* __restrict__ w, unsigned short* __restrict__ wbf)
{
    const int i = blockIdx.x * 256 + threadIdx.x;
    if (i < COUT * CIN * NK) {
        const int o = i / 288;
        const int r = i - o * 288;
        const int c = r / 9;
        const int j = r - c * 9;
        unsigned u = __float_as_uint(w[i]);
        wbf[o * 288 + j * 32 + c] =
            (unsigned short)((u + 0x7FFFu + ((u >> 16) & 1u)) >> 16);
    }
}

// ---------------------------------------------------------------------------
// Kernel 3: wave-autonomous fused kernel, dense-gather lane mapping.
// Grid = NT blocks x 256 thr (4 waves); wave w owns vertices w*4..w*4+3
// (ALL batches). Lane decomposition: coct = l>>4 (channel octet = MFMA
// k-octet), b = (l>>2)&3, vv = l&3; MFMA column arow = l&15 = b*4+vv.
// Gather = ONE dwordx4 per neighbor (16B/lane) from the coct-major xt row:
// each 64-lane instruction reads 4 full 256B vertex rows (zero waste,
// every 128B line requested exactly once per block -> 4x fewer line
// requests, 2x fewer VMEM instructions than the (vertex,octet) mapping).
// Interp/frag/MFMA structure identical to before (quad->coct, vloc->arow).
// ---------------------------------------------------------------------------
__global__ void __launch_bounds__(256) sparse_conv_mfma(
    const unsigned short* __restrict__ xt, const int* __restrict__ index,
    const float* __restrict__ itp, const unsigned short* __restrict__ wbf,
    const float* __restrict__ bias, float* __restrict__ out)
{
    __shared__ unsigned short Wlds[9 * 32 * 32];   // 18432 B, [j][o][c]
    __shared__ float itp_s[16 * 108];              //  6912 B, [vl][n][12]
    __shared__ int   idx_s[144];                   //   576 B

    const int t    = threadIdx.x;
    const int w    = t >> 6;                 // wave = vertex sub-group
    const int lane = t & 63;
    const int arow = lane & 15;              // MFMA row/col index = b*4+vv
    const int coct = lane >> 4;              // channel octet = k-octet
    const int b    = (lane >> 2) & 3;        // batch
    const int vv   = lane & 3;               // vertex within wave
    const int vl   = w * 4 + vv;             // block-local vertex 0..15
    const int tile = blockIdx.x;

    // bias -> regs (tile-invariant)
    float bs0[4], bs1[4];
    #pragma unroll
    for (int r = 0; r < 4; ++r) {
        bs0[r] = bias[coct * 4 + r];
        bs1[r] = bias[coct * 4 + 16 + r];
    }

    // stage Wlds: dst 16B-chunk n -> (j = n>>7, o = (n>>2)&31, cq = n&3)
    // src chunk in wbf (already k'-ordered) = o*36 + j*4 + cq
    #pragma unroll
    for (int r = 0; r < 5; ++r) {
        const int n = t + r * 256;
        if (n < 1152) {
            const int j  = n >> 7;
            const int o  = (n >> 2) & 31;
            const int cq = n & 3;
            ((uint4*)Wlds)[n] = ((const uint4*)wbf)[o * 36 + j * 4 + cq];
        }
    }
    if (t < 144) {
        const size_t bix = (size_t)tile * 144 + t;
        idx_s[t] = (bix < (size_t)NV9) ? index[bix] : 0;
    }
    {
        float itpv[6];
        const size_t base = (size_t)tile * 1296;
        #pragma unroll
        for (int i = 0; i < 6; ++i) {
            const int o = i * 256 + t;
            itpv[i] = (o < 1296 && base + o < (size_t)NV81) ? itp[base + o]
                                                            : 0.0f;
        }
        #pragma unroll
        for (int i = 0; i < 6; ++i) {
            const int o = i * 256 + t;
            if (o < 1296) {
                const int vli = o / 81;
                const int r2 = o - vli * 81;
                const int kk = r2 / 9;
                const int jj = r2 - kk * 9;
                itp_s[vli * 108 + kk * 12 + jj] = itpv[i];
            }
        }
    }
    __syncthreads();                         // the only barrier

    // neighbor ids for this lane's vertex (16-way broadcast LDS reads)
    int nbr[NK];
    #pragma unroll
    for (int n = 0; n < NK; ++n) nbr[n] = idx_s[vl * 9 + n];

    // gathers: one dense dwordx4 per neighbor
    // byte addr = nbr*256 + coct*64 + b*16  (16B aligned, 8 channels)
    const unsigned short* gbase = xt + coct * 32 + b * 8;
    uint4 g[NK];
    #pragma unroll
    for (int n = 0; n < NK; ++n)
        g[n] = *(const uint4*)(gbase + (size_t)nbr[n] * 128);

    unsigned frag[9][4];                     // B-frags, built in registers
    unsigned nzbits = 0;
    const float* ib = &itp_s[vl * 108];

    #pragma unroll
    for (int h = 0; h < 2; ++h) {            // 4 channels per half
        f32x2 acc2[4][4];
        float acc8[4];
        #pragma unroll
        for (int n = 0; n < NK; ++n) {
            const uint2 gk = h ? make_uint2(g[n].z, g[n].w)
                               : make_uint2(g[n].x, g[n].y);
            nzbits |= (gk.x | gk.y) & 0x7FFF7FFFu;
            f32x2 gp01, gp23;
            gp01.x = __uint_as_float(gk.x << 16);
            gp01.y = __uint_as_float(gk.x & 0xFFFF0000u);
            gp23.x = __uint_as_float(gk.y << 16);
            gp23.y = __uint_as_float(gk.y & 0xFFFF0000u);
            const float* ir = ib + n * 12;
            const f32x4 ra = *(const f32x4*)ir;
            const f32x4 rb = *(const f32x4*)(ir + 4);
            const float r8 = ir[8];
            f32x2 rp[4];
            rp[0] = __builtin_shufflevector(ra, ra, 0, 1);
            rp[1] = __builtin_shufflevector(ra, ra, 2, 3);
            rp[2] = __builtin_shufflevector(rb, rb, 0, 1);
            rp[3] = __builtin_shufflevector(rb, rb, 2, 3);
            if (n == 0) {
                #pragma unroll
                for (int jp = 0; jp < 4; ++jp) {
                    PKMUL_L(acc2[0][jp], gp01, rp[jp]);
                    PKMUL_H(acc2[1][jp], gp01, rp[jp]);
                    PKMUL_L(acc2[2][jp], gp23, rp[jp]);
                    PKMUL_H(acc2[3][jp], gp23, rp[jp]);
                }
                acc8[0] = gp01.x * r8; acc8[1] = gp01.y * r8;
                acc8[2] = gp23.x * r8; acc8[3] = gp23.y * r8;
            } else {
                #pragma unroll
                for (int jp = 0; jp < 4; ++jp) {
                    PKFMA_L(acc2[0][jp], gp01, rp[jp]);
                    PKFMA_H(acc2[1][jp], gp01, rp[jp]);
                    PKFMA_L(acc2[2][jp], gp23, rp[jp]);
                    PKFMA_H(acc2[3][jp], gp23, rp[jp]);
                }
                acc8[0] += gp01.x * r8; acc8[1] += gp01.y * r8;
                acc8[2] += gp23.x * r8; acc8[3] += gp23.y * r8;
            }
        }
        // pack this half's 4 channels into frag dwords 2h, 2h+1
        #pragma unroll
        for (int ks = 0; ks < 9; ++ks) {
            frag[ks][2 * h]     = pkbf(ACC(0, ks), ACC(1, ks));
            frag[ks][2 * h + 1] = pkbf(ACC(2, ks), ACC(3, ks));
        }
    }

    // nz over all 32 channels of this lane's (b, vv) column:
    // OR across the coct lane-bits (bits 4 and 5)
    unsigned nzw = nzbits;
    nzw |= __shfl_xor(nzw, 16);
    nzw |= __shfl_xor(nzw, 32);

    // MFMA: 9 K'-steps x 2 o-halves; A = Wlds[j][o][c] b128 reads
    f32x4 c0 = {0.f, 0.f, 0.f, 0.f};
    f32x4 c1 = {0.f, 0.f, 0.f, 0.f};
    #pragma unroll
    for (int ks = 0; ks < 9; ++ks) {
        union { uint4 u; bf16x8 v; } bfr;
        bfr.u.x = frag[ks][0]; bfr.u.y = frag[ks][1];
        bfr.u.z = frag[ks][2]; bfr.u.w = frag[ks][3];
        const bf16x8 wa0 =
            *(const bf16x8*)&Wlds[(ks * 32 + arow) * 32 + coct * 8];
        const bf16x8 wa1 =
            *(const bf16x8*)&Wlds[(ks * 32 + arow + 16) * 32 + coct * 8];
        c0 = __builtin_amdgcn_mfma_f32_16x16x32_bf16(wa0, bfr.v, c0, 0, 0, 0);
        c1 = __builtin_amdgcn_mfma_f32_16x16x32_bf16(wa1, bfr.v, c1, 0, 0, 0);
    }

    // epilogue: C col = arow = b*4+vv, row o = coct*4+r (+16)
    const int vglob = tile * 16 + vl;
    if (vglob < NV) {
        const float m = nzw ? 1.0f : 0.0f;
        float* ob = out + (size_t)b * (COUT * NV) + vglob;
        #pragma unroll
        for (int r = 0; r < 4; ++r) {
            ob[(size_t)(coct * 4 + r) * NV]      = (c0[r] + bs0[r]) * m;
            ob[(size_t)(coct * 4 + 16 + r) * NV] = (c1[r] + bs1[r]) * m;
        }
    }
}

// ---------------------------------------------------------------------------
extern "C" void kernel_launch(void* const* d_in, const int* in_sizes, int n_in,
                              void* d_out, int out_size, void* d_ws, size_t ws_size,
                              hipStream_t stream)
{
    const float* x     = (const float*)d_in[0];
    const int*   index = (const int*)  d_in[1];
    const float* itp   = (const float*)d_in[2];
    const float* w     = (const float*)d_in[3];
    const float* bias  = (const float*)d_in[4];
    float*       out   = (float*)d_out;

    unsigned short* xt  = (unsigned short*)d_ws;                 // 10.5 MB
    unsigned short* wbf = (unsigned short*)((char*)d_ws + (size_t)NV * 256);

    hipLaunchKernelGGL(convert_w_bf16, dim3((COUT * CIN * NK + 255) / 256),
                       dim3(256), 0, stream, w, wbf);
    const int vtiles = (NV + VT - 1) / VT;   // 161
    hipLaunchKernelGGL(transpose_x_bf16, dim3(vtiles * NBS), dim3(256), 0,
                       stream, x, (unsigned*)xt);
    hipLaunchKernelGGL(sparse_conv_mfma, dim3(NT), dim3(256), 0,
                       stream, xt, index, itp, wbf, bias, out);
}

// Round 3
// 128.264 us; speedup vs baseline: 1.0594x; 1.0594x over previous
//
#include <hip/hip_runtime.h>
#include <hip/hip_bf16.h>

#define NV 40962
#define NK 9
#define CIN 32
#define COUT 32
#define NBS 4
#define VT 256                 // transpose v-tile
#define TP 260                 // transpose LDS row stride (dwords)
#define NT 2561                // v-tiles of 16 in main kernel
#define NB 1281                // main-kernel blocks (2 tiles each)
#define NV81 (NV * 81)
#define NV9  (NV * 9)

typedef __attribute__((ext_vector_type(8))) short bf16x8;
typedef __attribute__((ext_vector_type(4))) float f32x4;
typedef __attribute__((ext_vector_type(2))) float f32x2;

// ---- packed f32 FMA/MUL, src0 broadcast from pair half (VOP3P op_sel)
#define PKFMA_L(A, G, R) asm("v_pk_fma_f32 %0, %1, %2, %0 op_sel:[0,0,0] op_sel_hi:[0,1,1]" : "+v"(A) : "v"(G), "v"(R))
#define PKFMA_H(A, G, R) asm("v_pk_fma_f32 %0, %1, %2, %0 op_sel:[1,0,0] op_sel_hi:[1,1,1]" : "+v"(A) : "v"(G), "v"(R))
#define PKMUL_L(A, G, R) asm("v_pk_mul_f32 %0, %1, %2 op_sel:[0,0] op_sel_hi:[0,1]" : "=v"(A) : "v"(G), "v"(R))
#define PKMUL_H(A, G, R) asm("v_pk_mul_f32 %0, %1, %2 op_sel:[1,0] op_sel_hi:[1,1]" : "=v"(A) : "v"(G), "v"(R))

#define ACC(cc, j) ((j) == 8 ? acc8[cc] : (((j) & 1) ? acc2[cc][(j) >> 1].y \
                                                     : acc2[cc][(j) >> 1].x))

// f32 pair -> packed bf16 dword (a=low), via v_cvt_pk_bf16_f32 (RNE)
__device__ __forceinline__ unsigned pkbf(float a, float b) {
    union { __hip_bfloat162 h2; unsigned u; } cv;
    cv.h2 = __float22bfloat162_rn(make_float2(a, b));
    return cv.u;
}

// ---------------------------------------------------------------------------
// Kernel 1: x [128 rows=(b*32+c)][V] f32 -> xt [v][coct(4)][b(4)][8ch] bf16
// ---------------------------------------------------------------------------
__global__ void __launch_bounds__(256) transpose_x_bf16(
    const float* __restrict__ x, unsigned* __restrict__ xtw)
{
    __shared__ unsigned T[16 * TP];
    const int b  = blockIdx.x & 3;
    const int v0 = (blockIdx.x >> 2) * VT;
    const int t  = threadIdx.x;
    const int w  = t >> 6;
    const int L  = t & 63;
    const bool full = (v0 + VT <= NV);

    #pragma unroll
    for (int i = 0; i < 4; ++i) {
        const int q = w + 4 * i;
        const float* rowA = x + (size_t)(b * 32 + 2 * q) * NV;
        const float* rowB = rowA + NV;
        #pragma unroll
        for (int h = 0; h < 2; ++h) {
            const int vl = 128 * h + 2 * L;
            float2 a, c;
            if (full) {
                a = *(const float2*)(rowA + v0 + vl);
                c = *(const float2*)(rowB + v0 + vl);
            } else {
                const int v = v0 + vl;
                a.x = (v     < NV) ? rowA[v]     : 0.0f;
                a.y = (v + 1 < NV) ? rowA[v + 1] : 0.0f;
                c.x = (v     < NV) ? rowB[v]     : 0.0f;
                c.y = (v + 1 < NV) ? rowB[v + 1] : 0.0f;
            }
            uint2 d;
            d.x = pkbf(a.x, c.x);
            d.y = pkbf(a.y, c.y);
            *(uint2*)&T[q * TP + vl] = d;
        }
    }
    __syncthreads();

    #pragma unroll
    for (int i = 0; i < 4; ++i) {
        const int vl = i * 64 + w * 16 + (L >> 2);
        const int u4 = L & 3;
        const int v  = v0 + vl;
        if (v < NV) {
            uint4 d;
            d.x = T[(4 * u4 + 0) * TP + vl];
            d.y = T[(4 * u4 + 1) * TP + vl];
            d.z = T[(4 * u4 + 2) * TP + vl];
            d.w = T[(4 * u4 + 3) * TP + vl];
            // row layout: [v][coct=u4][b][4 dwords] (byte = v*256 + u4*64 + b*16)
            *(uint4*)&xtw[(size_t)v * 64 + u4 * 16 + b * 4] = d;
        }
    }
}

// ---------------------------------------------------------------------------
// Kernel 2: conv weight f32 [o][c][j] -> bf16 wbf[o][k' = j*32 + c]
// ---------------------------------------------------------------------------
__global__ void __launch_bounds__(256) convert_w_bf16(
    const float* __restrict__ w, unsigned short* __restrict__ wbf)
{
    const int i = blockIdx.x * 256 + threadIdx.x;
    if (i < COUT * CIN * NK) {
        const int o = i / 288;
        const int r = i - o * 288;
        const int c = r / 9;
        const int j = r - c * 9;
        unsigned u = __float_as_uint(w[i]);
        wbf[o * 288 + j * 32 + c] =
            (unsigned short)((u + 0x7FFFu + ((u >> 16) & 1u)) >> 16);
    }
}

// ---------------------------------------------------------------------------
// Per-tile compute: interp (pk-fma) -> frag pack -> nz -> 18 MFMA -> store.
// Fully register-resident; g[9] are the tile's gathered uint4s.
// ---------------------------------------------------------------------------
__device__ __forceinline__ void tile_compute(
    const uint4* g, const float* __restrict__ ib,
    const unsigned short* __restrict__ Wlds,
    const float* bs0, const float* bs1, float* __restrict__ out,
    int tile, int vl, int arow, int coct, int b)
{
    unsigned frag[9][4];

    // nz over the lane's 8 channels (fold once; mask strips bf16 sign bits)
    unsigned nzbits = 0;
    #pragma unroll
    for (int n = 0; n < NK; ++n)
        nzbits |= (g[n].x | g[n].y | g[n].z | g[n].w);
    nzbits &= 0x7FFF7FFFu;

    #pragma unroll
    for (int h = 0; h < 2; ++h) {            // 4 channels per half
        f32x2 acc2[4][4];
        float acc8[4];
        #pragma unroll
        for (int n = 0; n < NK; ++n) {
            const uint2 gk = h ? make_uint2(g[n].z, g[n].w)
                               : make_uint2(g[n].x, g[n].y);
            f32x2 gp01, gp23;
            gp01.x = __uint_as_float(gk.x << 16);
            gp01.y = __uint_as_float(gk.x & 0xFFFF0000u);
            gp23.x = __uint_as_float(gk.y << 16);
            gp23.y = __uint_as_float(gk.y & 0xFFFF0000u);
            const float* ir = ib + n * 12;
            const f32x4 ra = *(const f32x4*)ir;
            const f32x4 rb = *(const f32x4*)(ir + 4);
            const float r8 = ir[8];
            f32x2 rp[4];
            rp[0] = __builtin_shufflevector(ra, ra, 0, 1);
            rp[1] = __builtin_shufflevector(ra, ra, 2, 3);
            rp[2] = __builtin_shufflevector(rb, rb, 0, 1);
            rp[3] = __builtin_shufflevector(rb, rb, 2, 3);
            if (n == 0) {
                #pragma unroll
                for (int jp = 0; jp < 4; ++jp) {
                    PKMUL_L(acc2[0][jp], gp01, rp[jp]);
                    PKMUL_H(acc2[1][jp], gp01, rp[jp]);
                    PKMUL_L(acc2[2][jp], gp23, rp[jp]);
                    PKMUL_H(acc2[3][jp], gp23, rp[jp]);
                }
                acc8[0] = gp01.x * r8; acc8[1] = gp01.y * r8;
                acc8[2] = gp23.x * r8; acc8[3] = gp23.y * r8;
            } else {
                #pragma unroll
                for (int jp = 0; jp < 4; ++jp) {
                    PKFMA_L(acc2[0][jp], gp01, rp[jp]);
                    PKFMA_H(acc2[1][jp], gp01, rp[jp]);
                    PKFMA_L(acc2[2][jp], gp23, rp[jp]);
                    PKFMA_H(acc2[3][jp], gp23, rp[jp]);
                }
                acc8[0] += gp01.x * r8; acc8[1] += gp01.y * r8;
                acc8[2] += gp23.x * r8; acc8[3] += gp23.y * r8;
            }
        }
        #pragma unroll
        for (int ks = 0; ks < 9; ++ks) {
            frag[ks][2 * h]     = pkbf(ACC(0, ks), ACC(1, ks));
            frag[ks][2 * h + 1] = pkbf(ACC(2, ks), ACC(3, ks));
        }
    }

    // nz over all 32 channels of this lane's (b, vv) column (coct lane bits)
    unsigned nzw = nzbits;
    nzw |= __shfl_xor(nzw, 16);
    nzw |= __shfl_xor(nzw, 32);

    // MFMA: 9 K'-steps x 2 o-halves; A = Wlds[j][o][c] b128 reads
    f32x4 c0 = {0.f, 0.f, 0.f, 0.f};
    f32x4 c1 = {0.f, 0.f, 0.f, 0.f};
    #pragma unroll
    for (int ks = 0; ks < 9; ++ks) {
        union { uint4 u; bf16x8 v; } bfr;
        bfr.u.x = frag[ks][0]; bfr.u.y = frag[ks][1];
        bfr.u.z = frag[ks][2]; bfr.u.w = frag[ks][3];
        const bf16x8 wa0 =
            *(const bf16x8*)&Wlds[(ks * 32 + arow) * 32 + coct * 8];
        const bf16x8 wa1 =
            *(const bf16x8*)&Wlds[(ks * 32 + arow + 16) * 32 + coct * 8];
        c0 = __builtin_amdgcn_mfma_f32_16x16x32_bf16(wa0, bfr.v, c0, 0, 0, 0);
        c1 = __builtin_amdgcn_mfma_f32_16x16x32_bf16(wa1, bfr.v, c1, 0, 0, 0);
    }

    // epilogue: C col = arow = b*4+vv, row o = coct*4+r (+16)
    const int vglob = tile * 16 + vl;
    if (vglob < NV) {
        const float m = nzw ? 1.0f : 0.0f;
        float* ob = out + (size_t)b * (COUT * NV) + vglob;
        #pragma unroll
        for (int r = 0; r < 4; ++r) {
            ob[(size_t)(coct * 4 + r) * NV]      = (c0[r] + bs0[r]) * m;
            ob[(size_t)(coct * 4 + 16 + r) * NV] = (c1[r] + bs1[r]) * m;
        }
    }
}

// ---------------------------------------------------------------------------
// Kernel 3: 2 tiles per block, single barrier, deep-pipelined gathers.
// Grid = NB blocks x 256 thr. Stage Wlds + BOTH tiles' idx/itp up front,
// one __syncthreads, then issue all 18 gathers (A then B) back-to-back:
// tile B's L2/L3 latency hides under tile A's interp VALU + MFMA. Wlds
// staging (18.4 KB/block) is amortized over 2 tiles (was the largest
// fixed per-block cost at 2561 blocks).
// Lane decomposition: coct = l>>4 (k-octet), b = (l>>2)&3, vv = l&3;
// MFMA column arow = l&15 = b*4+vv; wave w owns vertices w*4..w*4+3.
// ---------------------------------------------------------------------------
__global__ void __launch_bounds__(256) sparse_conv_mfma(
    const unsigned short* __restrict__ xt, const int* __restrict__ index,
    const float* __restrict__ itp, const unsigned short* __restrict__ wbf,
    const float* __restrict__ bias, float* __restrict__ out)
{
    __shared__ unsigned short Wlds[9 * 32 * 32];   // 18432 B, [j][o][c]
    __shared__ float itp_s[2][16 * 108];           // 13824 B, [tt][vl][n][12]
    __shared__ int   idx_s[2][144];                //  1152 B

    const int t    = threadIdx.x;
    const int w    = t >> 6;
    const int lane = t & 63;
    const int arow = lane & 15;
    const int coct = lane >> 4;
    const int b    = (lane >> 2) & 3;
    const int vv   = lane & 3;
    const int vl   = w * 4 + vv;
    const int t0   = blockIdx.x * 2;

    // bias -> regs (tile-invariant)
    float bs0[4], bs1[4];
    #pragma unroll
    for (int r = 0; r < 4; ++r) {
        bs0[r] = bias[coct * 4 + r];
        bs1[r] = bias[coct * 4 + 16 + r];
    }

    // stage Wlds: dst 16B-chunk n -> (j = n>>7, o = (n>>2)&31, cq = n&3)
    #pragma unroll
    for (int r = 0; r < 5; ++r) {
        const int n = t + r * 256;
        if (n < 1152) {
            const int j  = n >> 7;
            const int o  = (n >> 2) & 31;
            const int cq = n & 3;
            ((uint4*)Wlds)[n] = ((const uint4*)wbf)[o * 36 + j * 4 + cq];
        }
    }
    // stage idx for both tiles
    #pragma unroll
    for (int tt = 0; tt < 2; ++tt) {
        if (t < 144) {
            const size_t bix = (size_t)(t0 + tt) * 144 + t;
            idx_s[tt][t] = (bix < (size_t)NV9) ? index[bix] : 0;
        }
    }
    // stage itp for both tiles (shared index math, contiguous streams)
    {
        float va[6], vb[6];
        const size_t baseA = (size_t)t0 * 1296;
        const size_t baseB = baseA + 1296;
        #pragma unroll
        for (int i = 0; i < 6; ++i) {
            const int o = i * 256 + t;
            va[i] = (o < 1296 && baseA + o < (size_t)NV81) ? itp[baseA + o]
                                                           : 0.0f;
            vb[i] = (o < 1296 && baseB + o < (size_t)NV81) ? itp[baseB + o]
                                                           : 0.0f;
        }
        #pragma unroll
        for (int i = 0; i < 6; ++i) {
            const int o = i * 256 + t;
            if (o < 1296) {
                const int vli = o / 81;
                const int r2  = o - vli * 81;
                const int kk  = r2 / 9;
                const int jj  = r2 - kk * 9;
                const int off = vli * 108 + kk * 12 + jj;
                itp_s[0][off] = va[i];
                itp_s[1][off] = vb[i];
            }
        }
    }
    __syncthreads();                         // the only barrier

    // neighbor ids for both tiles (broadcast LDS reads)
    int nbrA[NK], nbrB[NK];
    #pragma unroll
    for (int n = 0; n < NK; ++n) nbrA[n] = idx_s[0][vl * 9 + n];
    #pragma unroll
    for (int n = 0; n < NK; ++n) nbrB[n] = idx_s[1][vl * 9 + n];

    // issue ALL gathers up front: tile B's latency hides under tile A compute
    const unsigned short* gbase = xt + coct * 32 + b * 8;
    uint4 gA[NK], gB[NK];
    #pragma unroll
    for (int n = 0; n < NK; ++n)
        gA[n] = *(const uint4*)(gbase + (size_t)nbrA[n] * 128);
    #pragma unroll
    for (int n = 0; n < NK; ++n)
        gB[n] = *(const uint4*)(gbase + (size_t)nbrB[n] * 128);

    tile_compute(gA, &itp_s[0][vl * 108], Wlds, bs0, bs1, out,
                 t0, vl, arow, coct, b);
    tile_compute(gB, &itp_s[1][vl * 108], Wlds, bs0, bs1, out,
                 t0 + 1, vl, arow, coct, b);
}

// ---------------------------------------------------------------------------
extern "C" void kernel_launch(void* const* d_in, const int* in_sizes, int n_in,
                              void* d_out, int out_size, void* d_ws, size_t ws_size,
                              hipStream_t stream)
{
    const float* x     = (const float*)d_in[0];
    const int*   index = (const int*)  d_in[1];
    const float* itp   = (const float*)d_in[2];
    const float* w     = (const float*)d_in[3];
    const float* bias  = (const float*)d_in[4];
    float*       out   = (float*)d_out;

    unsigned short* xt  = (unsigned short*)d_ws;                 // 10.5 MB
    unsigned short* wbf = (unsigned short*)((char*)d_ws + (size_t)NV * 256);

    hipLaunchKernelGGL(convert_w_bf16, dim3((COUT * CIN * NK + 255) / 256),
                       dim3(256), 0, stream, w, wbf);
    const int vtiles = (NV + VT - 1) / VT;   // 161
    hipLaunchKernelGGL(transpose_x_bf16, dim3(vtiles * NBS), dim3(256), 0,
                       stream, x, (unsigned*)xt);
    hipLaunchKernelGGL(sparse_conv_mfma, dim3(NB), dim3(256), 0,
                       stream, xt, index, itp, wbf, bias, out);
}

// Round 4
// 124.151 us; speedup vs baseline: 1.0945x; 1.0331x over previous
//
#include <hip/hip_runtime.h>
#include <hip/hip_bf16.h>

#define NV 40962
#define NK 9
#define CIN 32
#define COUT 32
#define NT 2561                // v-tiles of 16 in main kernel
#define NV81 (NV * 81)
#define NV9  (NV * 9)

typedef __attribute__((ext_vector_type(8))) short bf16x8;
typedef __attribute__((ext_vector_type(4))) float f32x4;
typedef __attribute__((ext_vector_type(2))) float f32x2;

// ---- packed f32 FMA/MUL, src0 broadcast from pair half (VOP3P op_sel)
#define PKFMA_L(A, G, R) asm("v_pk_fma_f32 %0, %1, %2, %0 op_sel:[0,0,0] op_sel_hi:[0,1,1]" : "+v"(A) : "v"(G), "v"(R))
#define PKFMA_H(A, G, R) asm("v_pk_fma_f32 %0, %1, %2, %0 op_sel:[1,0,0] op_sel_hi:[1,1,1]" : "+v"(A) : "v"(G), "v"(R))
#define PKMUL_L(A, G, R) asm("v_pk_mul_f32 %0, %1, %2 op_sel:[0,0] op_sel_hi:[0,1]" : "=v"(A) : "v"(G), "v"(R))
#define PKMUL_H(A, G, R) asm("v_pk_mul_f32 %0, %1, %2 op_sel:[1,0] op_sel_hi:[1,1]" : "=v"(A) : "v"(G), "v"(R))

#define ACC(cc, j) ((j) == 8 ? acc8[cc] : (((j) & 1) ? acc2[cc][(j) >> 1].y \
                                                     : acc2[cc][(j) >> 1].x))

// f32 pair -> packed bf16 dword (a=low), via v_cvt_pk_bf16_f32 (RNE)
__device__ __forceinline__ unsigned pkbf(float a, float b) {
    union { __hip_bfloat162 h2; unsigned u; } cv;
    cv.h2 = __float22bfloat162_rn(make_float2(a, b));
    return cv.u;
}

// ---------------------------------------------------------------------------
// Kernel 1: transpose + weight-convert fused.
// x [128 rows=(b*32+c)][V] f32 -> xt [v][coct(4)][b(4)][8ch] bf16.
// One block owns a 64-vertex chunk for ALL 4 batches, so every 64B sector
// of xt is written FULL by one block (old version: 4 blocks on 4 different
// XCDs each wrote 16B/64B -> partial-sector write amplification).
// Blocks 0..35 additionally perform the conv-weight f32->bf16 K-permute
// (one elem/thread), removing the separate convert launch.
// ---------------------------------------------------------------------------
__global__ void __launch_bounds__(256) transpose_x_bf16(
    const float* __restrict__ x, unsigned* __restrict__ xtw,
    const float* __restrict__ w, unsigned short* __restrict__ wbf)
{
    __shared__ unsigned U[64 * 65];          // [v][64 dw + 1 pad], 16640 B
    const int t = threadIdx.x;

    // merged convert_w: wbf[o][k' = j*32 + c]
    const int ci = blockIdx.x * 256 + t;
    if (ci < COUT * CIN * NK) {
        const int o = ci / 288;
        const int r = ci - o * 288;
        const int c = r / 9;
        const int j = r - c * 9;
        unsigned u = __float_as_uint(w[ci]);
        wbf[o * 288 + j * 32 + c] =
            (unsigned short)((u + 0x7FFFu + ((u >> 16) & 1u)) >> 16);
    }

    const int v0  = blockIdx.x * 64;
    const int l16 = t & 15;
    const int p   = t >> 4;                  // row-pair group 0..15

    #pragma unroll
    for (int i = 0; i < 4; ++i) {
        const int q    = p * 4 + i;          // row-pair 0..63
        const int r0   = 2 * q;              // even row; r0+1 same batch
        const int bb   = r0 >> 5;
        const int c0   = r0 & 31;            // even channel
        const int dwb  = (c0 >> 3) * 16 + bb * 4 + ((c0 & 7) >> 1);
        const float* rowA = x + (size_t)r0 * NV + v0;
        const float* rowB = rowA + NV;
        #pragma unroll
        for (int hv = 0; hv < 2; ++hv) {
            const int v = l16 * 2 + hv * 32; // even, pair (v, v+1)
            float2 a = make_float2(0.f, 0.f), c2 = make_float2(0.f, 0.f);
            if (v0 + v < NV) {               // NV even: pair never crosses
                a  = *(const float2*)(rowA + v);
                c2 = *(const float2*)(rowB + v);
            }
            U[(v    ) * 65 + dwb] = pkbf(a.x, c2.x);
            U[(v + 1) * 65 + dwb] = pkbf(a.y, c2.y);
        }
    }
    __syncthreads();

    // write out: full 64B sectors (lanes qo=0..3 cover one sector)
    const int v  = t >> 2;
    const int qo = t & 3;
    if (v0 + v < NV) {
        #pragma unroll
        for (int j = 0; j < 4; ++j) {
            const int n = j * 4 + qo;        // 16B chunk id 0..15
            uint4 d;
            d.x = U[v * 65 + n * 4 + 0];
            d.y = U[v * 65 + n * 4 + 1];
            d.z = U[v * 65 + n * 4 + 2];
            d.w = U[v * 65 + n * 4 + 3];
            *(uint4*)&xtw[(size_t)(v0 + v) * 64 + n * 4] = d;
        }
    }
}

// ---------------------------------------------------------------------------
// Kernel 2: barrier-free wave-autonomous fused conv.
// Grid = NT blocks x 256 thr, NO __syncthreads. Each wave owns 4 vertices
// x 4 batches = the 16 MFMA columns; waves never couple.
// Lane: coct = l>>4 (k-octet), b = (l>>2)&3, vv = l&3, arow = l&15.
// Chain per wave: {idx load, itp loads, weight loads, gathers} all issued
// up front -> interp (pk-fma) -> frag pack -> 18 MFMA (A from regs) ->
// masked stores. Weights come straight from the L2-hot 18KB wbf table
// (no Wlds staging, no barrier drain, no LDS bank conflicts).
// itp staged into a PER-WAVE LDS slice with wave-synchronous ordering
// (in-order LDS pipe + wave_barrier; no s_barrier needed).
// ---------------------------------------------------------------------------
__global__ void __launch_bounds__(256, 2) sparse_conv_mfma(
    const unsigned short* __restrict__ xt, const int* __restrict__ index,
    const float* __restrict__ itp, const unsigned short* __restrict__ wbf,
    const float* __restrict__ bias, float* __restrict__ out)
{
    __shared__ float itp_s[4][4][108];       // per-wave slice, 6912 B total

    const int t    = threadIdx.x;
    const int w    = t >> 6;
    const int lane = t & 63;
    const int arow = lane & 15;
    const int coct = lane >> 4;
    const int b    = (lane >> 2) & 3;
    const int vv   = lane & 3;
    const int tile = blockIdx.x;

    // 1. idx load (lanes 0..35 carry the wave's 36 neighbor ids)
    int ia = tile * 144 + w * 36 + (lane < 36 ? lane : 35);
    ia = ia < NV9 ? ia : NV9 - 1;            // tail clamp: any valid id is safe
    const int myidx = index[ia];

    // 2. itp loads -> regs (contiguous, 324 floats per wave)
    float iv[6];
    const size_t ibase = (size_t)(tile * 16 + w * 4) * 81;
    #pragma unroll
    for (int i = 0; i < 6; ++i) {
        const int o = i * 64 + lane;
        iv[i] = (o < 324 && ibase + o < (size_t)NV81) ? itp[ibase + o] : 0.0f;
    }

    // 3. weight loads -> regs (18 x dwordx4 from L2-hot wbf)
    const unsigned short* wb0 = wbf + arow * 288 + coct * 8;
    uint4 wa0[NK], wa1[NK];
    #pragma unroll
    for (int ks = 0; ks < NK; ++ks) {
        wa0[ks] = *(const uint4*)(wb0 + ks * 32);
        wa1[ks] = *(const uint4*)(wb0 + 16 * 288 + ks * 32);
    }

    // bias -> regs
    float bs0[4], bs1[4];
    #pragma unroll
    for (int r = 0; r < 4; ++r) {
        bs0[r] = bias[coct * 4 + r];
        bs1[r] = bias[coct * 4 + 16 + r];
    }

    // 4. neighbor ids via shfl, then issue all 9 dense gathers
    int nbr[NK];
    #pragma unroll
    for (int n = 0; n < NK; ++n) nbr[n] = __shfl(myidx, vv * 9 + n);
    const unsigned short* gbase = xt + coct * 32 + b * 8;
    uint4 g[NK];
    #pragma unroll
    for (int n = 0; n < NK; ++n)
        g[n] = *(const uint4*)(gbase + (size_t)nbr[n] * 128);

    // 5. scatter itp into this wave's own LDS slice (wave-synchronous)
    #pragma unroll
    for (int i = 0; i < 6; ++i) {
        const int o = i * 64 + lane;
        if (o < 324) {
            const int vloc = o / 81;
            const int r2   = o - vloc * 81;
            const int kk   = r2 / 9;
            const int jj   = r2 - kk * 9;
            itp_s[w][vloc][kk * 12 + jj] = iv[i];
        }
    }
    __builtin_amdgcn_wave_barrier();         // pin write->read order (no s_barrier)

    // 6. interp + frag pack
    unsigned frag[9][4];
    unsigned nzbits = 0;
    #pragma unroll
    for (int n = 0; n < NK; ++n)
        nzbits |= (g[n].x | g[n].y | g[n].z | g[n].w);
    nzbits &= 0x7FFF7FFFu;

    const float* ib = &itp_s[w][vv][0];
    #pragma unroll
    for (int h = 0; h < 2; ++h) {            // 4 channels per half
        f32x2 acc2[4][4];
        float acc8[4];
        #pragma unroll
        for (int n = 0; n < NK; ++n) {
            const uint2 gk = h ? make_uint2(g[n].z, g[n].w)
                               : make_uint2(g[n].x, g[n].y);
            f32x2 gp01, gp23;
            gp01.x = __uint_as_float(gk.x << 16);
            gp01.y = __uint_as_float(gk.x & 0xFFFF0000u);
            gp23.x = __uint_as_float(gk.y << 16);
            gp23.y = __uint_as_float(gk.y & 0xFFFF0000u);
            const float* ir = ib + n * 12;
            const f32x4 ra = *(const f32x4*)ir;
            const f32x4 rb = *(const f32x4*)(ir + 4);
            const float r8 = ir[8];
            f32x2 rp[4];
            rp[0] = __builtin_shufflevector(ra, ra, 0, 1);
            rp[1] = __builtin_shufflevector(ra, ra, 2, 3);
            rp[2] = __builtin_shufflevector(rb, rb, 0, 1);
            rp[3] = __builtin_shufflevector(rb, rb, 2, 3);
            if (n == 0) {
                #pragma unroll
                for (int jp = 0; jp < 4; ++jp) {
                    PKMUL_L(acc2[0][jp], gp01, rp[jp]);
                    PKMUL_H(acc2[1][jp], gp01, rp[jp]);
                    PKMUL_L(acc2[2][jp], gp23, rp[jp]);
                    PKMUL_H(acc2[3][jp], gp23, rp[jp]);
                }
                acc8[0] = gp01.x * r8; acc8[1] = gp01.y * r8;
                acc8[2] = gp23.x * r8; acc8[3] = gp23.y * r8;
            } else {
                #pragma unroll
                for (int jp = 0; jp < 4; ++jp) {
                    PKFMA_L(acc2[0][jp], gp01, rp[jp]);
                    PKFMA_H(acc2[1][jp], gp01, rp[jp]);
                    PKFMA_L(acc2[2][jp], gp23, rp[jp]);
                    PKFMA_H(acc2[3][jp], gp23, rp[jp]);
                }
                acc8[0] += gp01.x * r8; acc8[1] += gp01.y * r8;
                acc8[2] += gp23.x * r8; acc8[3] += gp23.y * r8;
            }
        }
        #pragma unroll
        for (int ks = 0; ks < 9; ++ks) {
            frag[ks][2 * h]     = pkbf(ACC(0, ks), ACC(1, ks));
            frag[ks][2 * h + 1] = pkbf(ACC(2, ks), ACC(3, ks));
        }
    }

    // nz over all 32 channels of this lane's (b, vv) column (coct lane bits)
    unsigned nzw = nzbits;
    nzw |= __shfl_xor(nzw, 16);
    nzw |= __shfl_xor(nzw, 32);

    // 7. MFMA: 9 K'-steps x 2 o-halves; A-operand straight from registers
    f32x4 c0 = {0.f, 0.f, 0.f, 0.f};
    f32x4 c1 = {0.f, 0.f, 0.f, 0.f};
    #pragma unroll
    for (int ks = 0; ks < 9; ++ks) {
        union { uint4 u; bf16x8 v; } bfr, au0, au1;
        bfr.u.x = frag[ks][0]; bfr.u.y = frag[ks][1];
        bfr.u.z = frag[ks][2]; bfr.u.w = frag[ks][3];
        au0.u = wa0[ks];
        au1.u = wa1[ks];
        c0 = __builtin_amdgcn_mfma_f32_16x16x32_bf16(au0.v, bfr.v, c0, 0, 0, 0);
        c1 = __builtin_amdgcn_mfma_f32_16x16x32_bf16(au1.v, bfr.v, c1, 0, 0, 0);
    }

    // 8. epilogue: C col = arow = b*4+vv, row o = coct*4+r (+16)
    const int vglob = tile * 16 + w * 4 + vv;
    if (vglob < NV) {
        const float m = nzw ? 1.0f : 0.0f;
        float* ob = out + (size_t)b * (COUT * NV) + vglob;
        #pragma unroll
        for (int r = 0; r < 4; ++r) {
            ob[(size_t)(coct * 4 + r) * NV]      = (c0[r] + bs0[r]) * m;
            ob[(size_t)(coct * 4 + 16 + r) * NV] = (c1[r] + bs1[r]) * m;
        }
    }
}

// ---------------------------------------------------------------------------
extern "C" void kernel_launch(void* const* d_in, const int* in_sizes, int n_in,
                              void* d_out, int out_size, void* d_ws, size_t ws_size,
                              hipStream_t stream)
{
    const float* x     = (const float*)d_in[0];
    const int*   index = (const int*)  d_in[1];
    const float* itp   = (const float*)d_in[2];
    const float* w     = (const float*)d_in[3];
    const float* bias  = (const float*)d_in[4];
    float*       out   = (float*)d_out;

    unsigned short* xt  = (unsigned short*)d_ws;                 // 10.5 MB
    unsigned short* wbf = (unsigned short*)((char*)d_ws + (size_t)NV * 256);

    const int vchunks = (NV + 63) / 64;      // 641 (>= 36 convert blocks)
    hipLaunchKernelGGL(transpose_x_bf16, dim3(vchunks), dim3(256), 0,
                       stream, x, (unsigned*)xt, w, wbf);
    hipLaunchKernelGGL(sparse_conv_mfma, dim3(NT), dim3(256), 0,
                       stream, xt, index, itp, wbf, bias, out);
}